// Round 11
// baseline (605.484 us; speedup 1.0000x reference)
//

#include <hip/hip_runtime.h>
#include <hip/hip_bf16.h>

#define DD 384
#define NH 6
#define DHID 768

typedef __attribute__((ext_vector_type(8))) short bf16x8;
typedef __attribute__((ext_vector_type(4))) float f32x4;

__device__ __forceinline__ void gload_lds16(const void* gsrc, void* ldst) {
  __builtin_amdgcn_global_load_lds((const __attribute__((address_space(1))) void*)gsrc,
                                   (__attribute__((address_space(3))) void*)ldst,
                                   16, 0, 0);
}

__device__ __forceinline__ float b2f(unsigned short u) {
  union { unsigned int i; float f; } c;
  c.i = (unsigned int)u << 16;
  return c.f;
}

__device__ __forceinline__ short f2bf(float x) {
  union { __hip_bfloat16 h; short s; } u;
  u.h = __float2bfloat16(x);
  return u.s;
}

// ---------------- BatchNorm ----------------
__global__ __launch_bounds__(384) void bn_stats_k(const float* __restrict__ x, float* __restrict__ sums,
                                                  float* __restrict__ sq, int N, int rpb) {
  int d = threadIdx.x;
  int r0 = blockIdx.x * rpb;
  int r1 = min(r0 + rpb, N);
  float s = 0.f, ss = 0.f;
  for (int r = r0; r < r1; ++r) {
    float v = x[(size_t)r * DD + d];
    s += v; ss += v * v;
  }
  atomicAdd(&sums[d], s);
  atomicAdd(&sq[d], ss);
}

__global__ void bn_finalize_k(const float* sums, const float* sq, const float* g, const float* b,
                              float* a, float* c, int N) {
  int d = blockIdx.x * blockDim.x + threadIdx.x;
  if (d >= DD) return;
  float inv = 1.f / (float)N;
  float mu = sums[d] * inv;
  float var = sq[d] * inv - mu * mu;
  float rs = rsqrtf(var + 1e-5f);
  a[d] = rs * g[d];
  c[d] = b[d] - mu * rs * g[d];
}

union BPack { ushort4 u; __hip_bfloat16 b[4]; };

__global__ void norm_to_bf16_k(const float* __restrict__ x, const float* __restrict__ a,
                               const float* __restrict__ c, __hip_bfloat16* __restrict__ h, int total4) {
  int i = blockIdx.x * blockDim.x + threadIdx.x;
  if (i >= total4) return;
  float4 v = ((const float4*)x)[i];
  int d0 = (i * 4) % DD;
  float4 av = *(const float4*)(a + d0);
  float4 cv = *(const float4*)(c + d0);
  BPack p;
  p.b[0] = __float2bfloat16(v.x * av.x + cv.x);
  p.b[1] = __float2bfloat16(v.y * av.y + cv.y);
  p.b[2] = __float2bfloat16(v.z * av.z + cv.z);
  p.b[3] = __float2bfloat16(v.w * av.w + cv.w);
  ((ushort4*)h)[i] = p.u;
}

__global__ void transpose_bf16_k(const float* __restrict__ in, __hip_bfloat16* __restrict__ out,
                                 int K, int Nout) {
  int i = blockIdx.x * blockDim.x + threadIdx.x;
  if (i >= K * Nout) return;
  int k = i / Nout, n = i % Nout;
  out[(size_t)n * K + k] = __float2bfloat16(in[i]);
}

__global__ void concat_bias_k(const float* bq, const float* bk, const float* bv, const float* bs,
                              float* out) {
  int i = blockIdx.x * blockDim.x + threadIdx.x;
  if (i >= 1536) return;
  float v = (i < 384) ? bq[i] : (i < 768) ? bk[i - 384] : (i < 1152) ? bv[i - 768] : bs[i - 1152];
  out[i] = v;
}

__global__ void add3_k(const float* __restrict__ x, const float* __restrict__ agg,
                       const float* __restrict__ skip, float* __restrict__ x1, int total4) {
  int i = blockIdx.x * blockDim.x + threadIdx.x;
  if (i >= total4) return;
  float4 a = ((const float4*)x)[i];
  float4 b = ((const float4*)agg)[i];
  float4 c = ((const float4*)skip)[i];
  float4 o;
  o.x = a.x + b.x + c.x; o.y = a.y + b.y + c.y;
  o.z = a.z + b.z + c.z; o.w = a.w + b.w + c.w;
  ((float4*)x1)[i] = o;
}

// ---------------- CSR build ----------------
__global__ void hist_k(const int* __restrict__ ei, int* __restrict__ deg, int E) {
  int i = blockIdx.x * blockDim.x + threadIdx.x;
  if (i < E) atomicAdd(&deg[ei[E + i]], 1);
}

__global__ __launch_bounds__(1024) void scan_k(const int* __restrict__ deg, int* __restrict__ row_start,
                                               int* __restrict__ cursor, int N) {
  __shared__ int part[1024];
  int t = threadIdx.x;
  int ch = (N + 1023) / 1024;
  int c0 = t * ch, c1 = min(c0 + ch, N);
  int s = 0;
  for (int i = c0; i < c1; ++i) s += deg[i];
  part[t] = s;
  __syncthreads();
  for (int off = 1; off < 1024; off <<= 1) {
    int v = (t >= off) ? part[t - off] : 0;
    __syncthreads();
    part[t] += v;
    __syncthreads();
  }
  int run = part[t] - s;
  for (int i = c0; i < c1; ++i) {
    row_start[i] = run; cursor[i] = run; run += deg[i];
  }
  if (t == 1023) row_start[N] = part[1023];
}

__global__ void scatter_k(const int* __restrict__ ei, int* __restrict__ cursor,
                          int* __restrict__ csr_src, int* __restrict__ csr_eid, int E) {
  int i = blockIdx.x * blockDim.x + threadIdx.x;
  if (i >= E) return;
  int s = ei[i], d = ei[E + i];
  int pos = atomicAdd(&cursor[d], 1);
  csr_src[pos] = s;
  csr_eid[pos] = i;
}

// ---------------- attention (one wave per node; 4x16-lane groups, 4 edges in flight) ----------------
__global__ __launch_bounds__(256) void attn_k(const __hip_bfloat16* __restrict__ qkv,
                                              const __hip_bfloat16* __restrict__ ebuf,
                                              const int* __restrict__ row_start,
                                              const int* __restrict__ csr_src,
                                              const int* __restrict__ csr_eid,
                                              float* __restrict__ agg, int N) {
  int wid = (blockIdx.x * blockDim.x + threadIdx.x) >> 6;
  int lane = threadIdx.x & 63;
  if (wid >= N) return;
  int g = lane >> 4, l = lane & 15;
  const ushort* qk = (const ushort*)qkv;
  const ushort* eu = (const ushort*)ebuf;
  float q[NH][4], acc[NH][4], psum[NH];
#pragma unroll
  for (int h = 0; h < NH; ++h) {
    ushort4 u = *(const ushort4*)&qk[(size_t)wid * 1152 + h * 64 + l * 4];
    q[h][0] = b2f(u.x); q[h][1] = b2f(u.y); q[h][2] = b2f(u.z); q[h][3] = b2f(u.w);
#pragma unroll
    for (int j = 0; j < 4; ++j) acc[h][j] = 0.f;
    psum[h] = 0.f;
  }
  int i0 = row_start[wid], i1 = row_start[wid + 1];
  for (int i = i0; i < i1; i += 4) {
    int e = i + g;
    bool valid = e < i1;
    int ec = valid ? e : i1 - 1;
    size_t sb = (size_t)csr_src[ec] * 1152;
    size_t eb = (size_t)csr_eid[ec] * 384;
    float ev[NH][4], p[NH];
#pragma unroll
    for (int h = 0; h < NH; ++h) {
      ushort4 ue = *(const ushort4*)&eu[eb + h * 64 + l * 4];
      ev[h][0] = b2f(ue.x); ev[h][1] = b2f(ue.y); ev[h][2] = b2f(ue.z); ev[h][3] = b2f(ue.w);
      ushort4 uk = *(const ushort4*)&qk[sb + 384 + h * 64 + l * 4];
      float t = q[h][0] * (b2f(uk.x) + ev[h][0]);
      t += q[h][1] * (b2f(uk.y) + ev[h][1]);
      t += q[h][2] * (b2f(uk.z) + ev[h][2]);
      t += q[h][3] * (b2f(uk.w) + ev[h][3]);
      t += __shfl_xor(t, 1);
      t += __shfl_xor(t, 2);
      t += __shfl_xor(t, 4);
      t += __shfl_xor(t, 8);
      p[h] = valid ? __expf(t * 0.125f) : 0.f;
    }
#pragma unroll
    for (int h = 0; h < NH; ++h) {
      ushort4 uv = *(const ushort4*)&qk[sb + 768 + h * 64 + l * 4];
      acc[h][0] += p[h] * (b2f(uv.x) + ev[h][0]);
      acc[h][1] += p[h] * (b2f(uv.y) + ev[h][1]);
      acc[h][2] += p[h] * (b2f(uv.z) + ev[h][2]);
      acc[h][3] += p[h] * (b2f(uv.w) + ev[h][3]);
      psum[h] += p[h];
    }
  }
#pragma unroll
  for (int h = 0; h < NH; ++h) {
#pragma unroll
    for (int j = 0; j < 4; ++j) {
      acc[h][j] += __shfl_xor(acc[h][j], 16);
      acc[h][j] += __shfl_xor(acc[h][j], 32);
    }
    psum[h] += __shfl_xor(psum[h], 16);
    psum[h] += __shfl_xor(psum[h], 32);
  }
  if (lane < 16) {
#pragma unroll
    for (int h = 0; h < NH; ++h) {
      float inv = psum[h] > 0.f ? 1.f / psum[h] : 0.f;
      float4 o;
      o.x = acc[h][0] * inv; o.y = acc[h][1] * inv;
      o.z = acc[h][2] * inv; o.w = acc[h][3] * inv;
      *(float4*)&agg[(size_t)wid * DD + h * 64 + l * 4] = o;
    }
  }
}

// ---------------- generic GEMM (col-fastest grid, 128x128 tile, BK=64, XOR-swizzled LDS) ----------------
// LDS layout: row r holds its 8 16B-chunks permuted by  phys = logical ^ (r&7).
// global_load_lds writes linearly, so the permutation is applied on the SOURCE address;
// ds_read side un-permutes with the same XOR (rule #21 both-sides involution).
#define BM 128
#define BN 128
#define BK 64

enum { M_QKVS = 0, M_BF16 = 1, M_GELU = 2, M_RES = 3 };

template <int MODE>
__global__ __launch_bounds__(256) void gemm_k(const __hip_bfloat16* __restrict__ A,
                                              const __hip_bfloat16* __restrict__ BT,
                                              const float* __restrict__ bias,
                                              const float* __restrict__ res,
                                              void* __restrict__ out0, void* __restrict__ out1,
                                              int M, int K, int Nn) {
  __shared__ short lA[BM * BK];   // 16 KB
  __shared__ short lB[BN * BK];   // 16 KB
  int t = threadIdx.x;
  int lane = t & 63, w = t >> 6;
  int wr = (w >> 1) * 64, wc = (w & 1) * 64;
  int row0 = blockIdx.y * BM, col0 = blockIdx.x * BN;   // col-fastest
  int lr = lane & 15, lk = lane >> 4;
  f32x4 acc[4][4] = {};

  for (int kt = 0; kt < K; kt += BK) {
    __syncthreads();
#pragma unroll
    for (int j = 0; j < 4; ++j) {
      int c = j * 256 + t;
      int r = c >> 3;
      int kcs = (c & 7) ^ (r & 7);             // pre-swizzled source chunk
      int wavebase = (j * 256 + w * 64) * 8;   // linear LDS dest (shorts)
      int gra = row0 + r; gra = gra < M ? gra : M - 1;
      gload_lds16(A + (size_t)gra * K + kt + kcs * 8, &lA[wavebase]);
      gload_lds16(BT + (size_t)(col0 + r) * K + kt + kcs * 8, &lB[wavebase]);
    }
    __syncthreads();
#pragma unroll
    for (int kk = 0; kk < 2; ++kk) {
      int p = (kk * 4 + lk) ^ (lr & 7);        // swizzled read chunk (row&7 == lr&7)
      bf16x8 af[4], bfr[4];
#pragma unroll
      for (int mi = 0; mi < 4; ++mi)
        af[mi] = *(const bf16x8*)&lA[(wr + mi * 16 + lr) * BK + p * 8];
#pragma unroll
      for (int ni = 0; ni < 4; ++ni)
        bfr[ni] = *(const bf16x8*)&lB[(wc + ni * 16 + lr) * BK + p * 8];
#pragma unroll
      for (int mi = 0; mi < 4; ++mi)
#pragma unroll
        for (int ni = 0; ni < 4; ++ni)
          acc[mi][ni] = __builtin_amdgcn_mfma_f32_16x16x32_bf16(af[mi], bfr[ni], acc[mi][ni], 0, 0, 0);
    }
  }

#pragma unroll
  for (int mi = 0; mi < 4; ++mi) {
#pragma unroll
    for (int r = 0; r < 4; ++r) {
      int row = row0 + wr + mi * 16 + lk * 4 + r;
      if (row >= M) continue;
#pragma unroll
      for (int ni = 0; ni < 4; ++ni) {
        int col = col0 + wc + ni * 16 + lr;
        float v = acc[mi][ni][r];
        if constexpr (MODE == M_QKVS) {
          v += bias[col];
          if (col < 1152)
            ((__hip_bfloat16*)out0)[(size_t)row * 1152 + col] = __float2bfloat16(v);
          else
            ((float*)out1)[(size_t)row * DD + (col - 1152)] = v;
        } else if constexpr (MODE == M_BF16) {
          ((__hip_bfloat16*)out0)[(size_t)row * Nn + col] = __float2bfloat16(v);
        } else if constexpr (MODE == M_GELU) {
          v += bias[col];
          v = 0.5f * v * (1.f + erff(v * 0.70710678118f));
          ((__hip_bfloat16*)out0)[(size_t)row * Nn + col] = __float2bfloat16(v);
        } else {  // M_RES
          v += bias[col];
          ((float*)out0)[(size_t)row * Nn + col] = v + res[(size_t)row * Nn + col];
        }
      }
    }
  }
}

// ---------------- edge GEMM, full-width: one block = 128 rows x ALL 384 cols, BK=64 ----------------
__global__ __launch_bounds__(256, 2) void gemm_edge_wide(const float* __restrict__ A,
                                                         const __hip_bfloat16* __restrict__ BT,
                                                         __hip_bfloat16* __restrict__ out, int M) {
  __shared__ short lA[BM * BK];          // 128 x 64 = 16 KB
  __shared__ short lB[DD * BK];          // 384 x 64 = 48 KB
  int t = threadIdx.x;
  int lane = t & 63, w = t >> 6;
  int wr = (w >> 1) * 64, wc = (w & 1) * 192;
  int row0 = blockIdx.x * BM;
  int lr = lane & 15, lk = lane >> 4;
  f32x4 acc[4][12] = {};

  for (int kt = 0; kt < DD; kt += BK) {
    __syncthreads();
    // B: 384 rows x 8 chunks = 3072 chunks, 12 per thread (source pre-swizzled)
#pragma unroll
    for (int pss = 0; pss < 12; ++pss) {
      int c = pss * 256 + t;
      int r = c >> 3;
      int kcs = (c & 7) ^ (r & 7);
      int wavebase = (pss * 256 + w * 64) * 8;
      gload_lds16(BT + (size_t)r * DD + kt + kcs * 8, &lB[wavebase]);
    }
    // A: f32 -> bf16 reg-staged, 1024 chunks, 4 per thread, written to swizzled slot
#pragma unroll
    for (int pss = 0; pss < 4; ++pss) {
      int c = pss * 256 + t;
      int r = c >> 3, kcl = c & 7;
      int gra = row0 + r; gra = gra < M ? gra : M - 1;
      const float4* ap = (const float4*)(A + (size_t)gra * DD + kt + kcl * 8);
      float4 f0 = ap[0], f1 = ap[1];
      bf16x8 v;
      v[0] = f2bf(f0.x); v[1] = f2bf(f0.y); v[2] = f2bf(f0.z); v[3] = f2bf(f0.w);
      v[4] = f2bf(f1.x); v[5] = f2bf(f1.y); v[6] = f2bf(f1.z); v[7] = f2bf(f1.w);
      *(__shared__ bf16x8*)&lA[r * BK + (kcl ^ (r & 7)) * 8] = v;
    }
    __syncthreads();
#pragma unroll
    for (int kk = 0; kk < 2; ++kk) {
      int p = (kk * 4 + lk) ^ (lr & 7);
      bf16x8 af[4];
#pragma unroll
      for (int mi = 0; mi < 4; ++mi)
        af[mi] = *(const bf16x8*)&lA[(wr + mi * 16 + lr) * BK + p * 8];
#pragma unroll
      for (int ni = 0; ni < 12; ++ni) {
        bf16x8 bfr = *(const bf16x8*)&lB[(wc + ni * 16 + lr) * BK + p * 8];
#pragma unroll
        for (int mi = 0; mi < 4; ++mi)
          acc[mi][ni] = __builtin_amdgcn_mfma_f32_16x16x32_bf16(af[mi], bfr, acc[mi][ni], 0, 0, 0);
      }
    }
  }

#pragma unroll
  for (int mi = 0; mi < 4; ++mi) {
#pragma unroll
    for (int r = 0; r < 4; ++r) {
      int row = row0 + wr + mi * 16 + lk * 4 + r;
      if (row >= M) continue;
#pragma unroll
      for (int ni = 0; ni < 12; ++ni) {
        int col = wc + ni * 16 + lr;
        out[(size_t)row * DD + col] = __float2bfloat16(acc[mi][ni][r]);
      }
    }
  }
}

// ---------------- host ----------------
extern "C" void kernel_launch(void* const* d_in, const int* in_sizes, int n_in,
                              void* d_out, int out_size, void* d_ws, size_t ws_size,
                              hipStream_t stream) {
  const float* x   = (const float*)d_in[0];
  const int*   ei  = (const int*)d_in[1];
  const float* ea  = (const float*)d_in[2];
  const float* g1  = (const float*)d_in[3];
  const float* b1  = (const float*)d_in[4];
  const float* Wq  = (const float*)d_in[5];
  const float* bq  = (const float*)d_in[6];
  const float* Wk  = (const float*)d_in[7];
  const float* bk  = (const float*)d_in[8];
  const float* Wv  = (const float*)d_in[9];
  const float* bv  = (const float*)d_in[10];
  const float* We  = (const float*)d_in[11];
  const float* Wsk = (const float*)d_in[12];
  const float* bsk = (const float*)d_in[13];
  const float* g2  = (const float*)d_in[14];
  const float* b2  = (const float*)d_in[15];
  const float* W1  = (const float*)d_in[16];
  const float* bm1 = (const float*)d_in[17];
  const float* W2  = (const float*)d_in[18];
  const float* bm2 = (const float*)d_in[19];

  int N = in_sizes[0] / DD;
  int E = in_sizes[1] / 2;

  char* ws = (char*)d_ws;
  size_t off = 0;
  auto alloc = [&](size_t bytes) -> char* {
    char* p = ws + off;
    off = (off + bytes + 255) & ~(size_t)255;
    return p;
  };

  float* bnsum = (float*)alloc(4 * DD * sizeof(float));  // sums1, sq1, sums2, sq2
  float* a1 = (float*)alloc(DD * 4);
  float* c1 = (float*)alloc(DD * 4);
  float* a2 = (float*)alloc(DD * 4);
  float* c2 = (float*)alloc(DD * 4);
  float* bqkvs = (float*)alloc(1536 * 4);
  __hip_bfloat16* WqkvsT = (__hip_bfloat16*)alloc((size_t)1536 * DD * 2);
  __hip_bfloat16* WeT = (__hip_bfloat16*)alloc((size_t)DD * DD * 2);
  __hip_bfloat16* W1T = (__hip_bfloat16*)alloc((size_t)DHID * DD * 2);
  __hip_bfloat16* W2T = (__hip_bfloat16*)alloc((size_t)DD * DHID * 2);
  __hip_bfloat16* hbuf = (__hip_bfloat16*)alloc((size_t)N * DD * 2);   // h, later h2
  __hip_bfloat16* qkv = (__hip_bfloat16*)alloc((size_t)N * 1152 * 2);
  float* skip = (float*)alloc((size_t)N * DD * 4);
  __hip_bfloat16* ebuf = (__hip_bfloat16*)alloc((size_t)E * DD * 2);
  float* agg = (float*)alloc((size_t)N * DD * 4);
  float* x1 = (float*)alloc((size_t)N * DD * 4);
  __hip_bfloat16* hid = (__hip_bfloat16*)alloc((size_t)N * DHID * 2);
  int* deg = (int*)alloc((size_t)N * 4);
  int* cursor = (int*)alloc((size_t)N * 4);
  int* row_start = (int*)alloc((size_t)(N + 1) * 4);
  int* csr_src = (int*)alloc((size_t)E * 4);
  int* csr_eid = (int*)alloc((size_t)E * 4);
  (void)ws_size; (void)n_in; (void)out_size;

  hipMemsetAsync(bnsum, 0, 4 * DD * sizeof(float), stream);
  hipMemsetAsync(deg, 0, (size_t)N * 4, stream);

  int rpb = 128, sgrid = (N + rpb - 1) / rpb;
  bn_stats_k<<<sgrid, DD, 0, stream>>>(x, bnsum, bnsum + DD, N, rpb);
  bn_finalize_k<<<2, 256, 0, stream>>>(bnsum, bnsum + DD, g1, b1, a1, c1, N);

  int t4 = N * DD / 4;
  norm_to_bf16_k<<<(t4 + 255) / 256, 256, 0, stream>>>(x, a1, c1, hbuf, t4);

  int wgrid = (DD * DD + 255) / 256;
  transpose_bf16_k<<<wgrid, 256, 0, stream>>>(Wq, WqkvsT, DD, DD);
  transpose_bf16_k<<<wgrid, 256, 0, stream>>>(Wk, WqkvsT + (size_t)DD * DD, DD, DD);
  transpose_bf16_k<<<wgrid, 256, 0, stream>>>(Wv, WqkvsT + (size_t)2 * DD * DD, DD, DD);
  transpose_bf16_k<<<wgrid, 256, 0, stream>>>(Wsk, WqkvsT + (size_t)3 * DD * DD, DD, DD);
  transpose_bf16_k<<<wgrid, 256, 0, stream>>>(We, WeT, DD, DD);
  transpose_bf16_k<<<(DD * DHID + 255) / 256, 256, 0, stream>>>(W1, W1T, DD, DHID);
  transpose_bf16_k<<<(DHID * DD + 255) / 256, 256, 0, stream>>>(W2, W2T, DHID, DD);
  concat_bias_k<<<6, 256, 0, stream>>>(bq, bk, bv, bsk, bqkvs);

  // col-fastest grids: (ncols, nrows)
  dim3 gqkvs(1536 / BN, (N + BM - 1) / BM);
  gemm_k<M_QKVS><<<gqkvs, 256, 0, stream>>>(hbuf, WqkvsT, bqkvs, nullptr, qkv, skip, N, DD, 1536);

  // edge GEMM: full-width blocks, A read exactly once
  gemm_edge_wide<<<(E + BM - 1) / BM, 256, 0, stream>>>(ea, WeT, ebuf, E);

  hist_k<<<(E + 255) / 256, 256, 0, stream>>>(ei, deg, E);
  scan_k<<<1, 1024, 0, stream>>>(deg, row_start, cursor, N);
  scatter_k<<<(E + 255) / 256, 256, 0, stream>>>(ei, cursor, csr_src, csr_eid, E);

  attn_k<<<(N * 64 + 255) / 256, 256, 0, stream>>>(qkv, ebuf, row_start, csr_src, csr_eid, agg, N);

  add3_k<<<(t4 + 255) / 256, 256, 0, stream>>>(x, agg, skip, x1, t4);

  bn_stats_k<<<sgrid, DD, 0, stream>>>(x1, bnsum + 2 * DD, bnsum + 3 * DD, N, rpb);
  bn_finalize_k<<<2, 256, 0, stream>>>(bnsum + 2 * DD, bnsum + 3 * DD, g2, b2, a2, c2, N);
  norm_to_bf16_k<<<(t4 + 255) / 256, 256, 0, stream>>>(x1, a2, c2, hbuf, t4);

  dim3 gm1(DHID / BN, (N + BM - 1) / BM);
  gemm_k<M_GELU><<<gm1, 256, 0, stream>>>(hbuf, W1T, bm1, nullptr, hid, nullptr, N, DD, DHID);

  dim3 gm2(DD / BN, (N + BM - 1) / BM);
  gemm_k<M_RES><<<gm2, 256, 0, stream>>>(hid, W2T, bm2, x1, (float*)d_out, nullptr, N, DHID, DD);
}

// Round 12
// 597.598 us; speedup vs baseline: 1.0132x; 1.0132x over previous
//

#include <hip/hip_runtime.h>
#include <hip/hip_bf16.h>

#define DD 384
#define NH 6
#define DHID 768

typedef __attribute__((ext_vector_type(8))) short bf16x8;
typedef __attribute__((ext_vector_type(4))) float f32x4;

__device__ __forceinline__ void gload_lds16(const void* gsrc, void* ldst) {
  __builtin_amdgcn_global_load_lds((const __attribute__((address_space(1))) void*)gsrc,
                                   (__attribute__((address_space(3))) void*)ldst,
                                   16, 0, 0);
}

__device__ __forceinline__ float b2f(unsigned short u) {
  union { unsigned int i; float f; } c;
  c.i = (unsigned int)u << 16;
  return c.f;
}

__device__ __forceinline__ short f2bf(float x) {
  union { __hip_bfloat16 h; short s; } u;
  u.h = __float2bfloat16(x);
  return u.s;
}

// ---------------- BatchNorm ----------------
__global__ __launch_bounds__(384) void bn_stats_k(const float* __restrict__ x, float* __restrict__ sums,
                                                  float* __restrict__ sq, int N, int rpb) {
  int d = threadIdx.x;
  int r0 = blockIdx.x * rpb;
  int r1 = min(r0 + rpb, N);
  float s = 0.f, ss = 0.f;
  for (int r = r0; r < r1; ++r) {
    float v = x[(size_t)r * DD + d];
    s += v; ss += v * v;
  }
  atomicAdd(&sums[d], s);
  atomicAdd(&sq[d], ss);
}

__global__ void bn_finalize_k(const float* sums, const float* sq, const float* g, const float* b,
                              float* a, float* c, int N) {
  int d = blockIdx.x * blockDim.x + threadIdx.x;
  if (d >= DD) return;
  float inv = 1.f / (float)N;
  float mu = sums[d] * inv;
  float var = sq[d] * inv - mu * mu;
  float rs = rsqrtf(var + 1e-5f);
  a[d] = rs * g[d];
  c[d] = b[d] - mu * rs * g[d];
}

union BPack { ushort4 u; __hip_bfloat16 b[4]; };

__global__ void norm_to_bf16_k(const float* __restrict__ x, const float* __restrict__ a,
                               const float* __restrict__ c, __hip_bfloat16* __restrict__ h, int total4) {
  int i = blockIdx.x * blockDim.x + threadIdx.x;
  if (i >= total4) return;
  float4 v = ((const float4*)x)[i];
  int d0 = (i * 4) % DD;
  float4 av = *(const float4*)(a + d0);
  float4 cv = *(const float4*)(c + d0);
  BPack p;
  p.b[0] = __float2bfloat16(v.x * av.x + cv.x);
  p.b[1] = __float2bfloat16(v.y * av.y + cv.y);
  p.b[2] = __float2bfloat16(v.z * av.z + cv.z);
  p.b[3] = __float2bfloat16(v.w * av.w + cv.w);
  ((ushort4*)h)[i] = p.u;
}

__global__ void transpose_bf16_k(const float* __restrict__ in, __hip_bfloat16* __restrict__ out,
                                 int K, int Nout) {
  int i = blockIdx.x * blockDim.x + threadIdx.x;
  if (i >= K * Nout) return;
  int k = i / Nout, n = i % Nout;
  out[(size_t)n * K + k] = __float2bfloat16(in[i]);
}

__global__ void concat_bias_k(const float* bq, const float* bk, const float* bv, const float* bs,
                              float* out) {
  int i = blockIdx.x * blockDim.x + threadIdx.x;
  if (i >= 1536) return;
  float v = (i < 384) ? bq[i] : (i < 768) ? bk[i - 384] : (i < 1152) ? bv[i - 768] : bs[i - 1152];
  out[i] = v;
}

__global__ void add3_k(const float* __restrict__ x, const float* __restrict__ agg,
                       const float* __restrict__ skip, float* __restrict__ x1, int total4) {
  int i = blockIdx.x * blockDim.x + threadIdx.x;
  if (i >= total4) return;
  float4 a = ((const float4*)x)[i];
  float4 b = ((const float4*)agg)[i];
  float4 c = ((const float4*)skip)[i];
  float4 o;
  o.x = a.x + b.x + c.x; o.y = a.y + b.y + c.y;
  o.z = a.z + b.z + c.z; o.w = a.w + b.w + c.w;
  ((float4*)x1)[i] = o;
}

// ---------------- CSR build ----------------
__global__ void hist_k(const int* __restrict__ ei, int* __restrict__ deg, int E) {
  int i = blockIdx.x * blockDim.x + threadIdx.x;
  if (i < E) atomicAdd(&deg[ei[E + i]], 1);
}

__global__ __launch_bounds__(1024) void scan_k(const int* __restrict__ deg, int* __restrict__ row_start,
                                               int* __restrict__ cursor, int N) {
  __shared__ int part[1024];
  int t = threadIdx.x;
  int ch = (N + 1023) / 1024;
  int c0 = t * ch, c1 = min(c0 + ch, N);
  int s = 0;
  for (int i = c0; i < c1; ++i) s += deg[i];
  part[t] = s;
  __syncthreads();
  for (int off = 1; off < 1024; off <<= 1) {
    int v = (t >= off) ? part[t - off] : 0;
    __syncthreads();
    part[t] += v;
    __syncthreads();
  }
  int run = part[t] - s;
  for (int i = c0; i < c1; ++i) {
    row_start[i] = run; cursor[i] = run; run += deg[i];
  }
  if (t == 1023) row_start[N] = part[1023];
}

__global__ void scatter_k(const int* __restrict__ ei, int* __restrict__ cursor,
                          int* __restrict__ csr_src, int* __restrict__ csr_eid, int E) {
  int i = blockIdx.x * blockDim.x + threadIdx.x;
  if (i >= E) return;
  int s = ei[i], d = ei[E + i];
  int pos = atomicAdd(&cursor[d], 1);
  csr_src[pos] = s;
  csr_eid[pos] = i;
}

// ---------------- attention (one wave per node; 4x16-lane groups, 4 edges in flight) ----------------
__global__ __launch_bounds__(256) void attn_k(const __hip_bfloat16* __restrict__ qkv,
                                              const __hip_bfloat16* __restrict__ ebuf,
                                              const int* __restrict__ row_start,
                                              const int* __restrict__ csr_src,
                                              const int* __restrict__ csr_eid,
                                              float* __restrict__ agg, int N) {
  int wid = (blockIdx.x * blockDim.x + threadIdx.x) >> 6;
  int lane = threadIdx.x & 63;
  if (wid >= N) return;
  int g = lane >> 4, l = lane & 15;
  const ushort* qk = (const ushort*)qkv;
  const ushort* eu = (const ushort*)ebuf;
  float q[NH][4], acc[NH][4], psum[NH];
#pragma unroll
  for (int h = 0; h < NH; ++h) {
    ushort4 u = *(const ushort4*)&qk[(size_t)wid * 1152 + h * 64 + l * 4];
    q[h][0] = b2f(u.x); q[h][1] = b2f(u.y); q[h][2] = b2f(u.z); q[h][3] = b2f(u.w);
#pragma unroll
    for (int j = 0; j < 4; ++j) acc[h][j] = 0.f;
    psum[h] = 0.f;
  }
  int i0 = row_start[wid], i1 = row_start[wid + 1];
  for (int i = i0; i < i1; i += 4) {
    int e = i + g;
    bool valid = e < i1;
    int ec = valid ? e : i1 - 1;
    size_t sb = (size_t)csr_src[ec] * 1152;
    size_t eb = (size_t)csr_eid[ec] * 384;
    float ev[NH][4], p[NH];
#pragma unroll
    for (int h = 0; h < NH; ++h) {
      ushort4 ue = *(const ushort4*)&eu[eb + h * 64 + l * 4];
      ev[h][0] = b2f(ue.x); ev[h][1] = b2f(ue.y); ev[h][2] = b2f(ue.z); ev[h][3] = b2f(ue.w);
      ushort4 uk = *(const ushort4*)&qk[sb + 384 + h * 64 + l * 4];
      float t = q[h][0] * (b2f(uk.x) + ev[h][0]);
      t += q[h][1] * (b2f(uk.y) + ev[h][1]);
      t += q[h][2] * (b2f(uk.z) + ev[h][2]);
      t += q[h][3] * (b2f(uk.w) + ev[h][3]);
      t += __shfl_xor(t, 1);
      t += __shfl_xor(t, 2);
      t += __shfl_xor(t, 4);
      t += __shfl_xor(t, 8);
      p[h] = valid ? __expf(t * 0.125f) : 0.f;
    }
#pragma unroll
    for (int h = 0; h < NH; ++h) {
      ushort4 uv = *(const ushort4*)&qk[sb + 768 + h * 64 + l * 4];
      acc[h][0] += p[h] * (b2f(uv.x) + ev[h][0]);
      acc[h][1] += p[h] * (b2f(uv.y) + ev[h][1]);
      acc[h][2] += p[h] * (b2f(uv.z) + ev[h][2]);
      acc[h][3] += p[h] * (b2f(uv.w) + ev[h][3]);
      psum[h] += p[h];
    }
  }
#pragma unroll
  for (int h = 0; h < NH; ++h) {
#pragma unroll
    for (int j = 0; j < 4; ++j) {
      acc[h][j] += __shfl_xor(acc[h][j], 16);
      acc[h][j] += __shfl_xor(acc[h][j], 32);
    }
    psum[h] += __shfl_xor(psum[h], 16);
    psum[h] += __shfl_xor(psum[h], 32);
  }
  if (lane < 16) {
#pragma unroll
    for (int h = 0; h < NH; ++h) {
      float inv = psum[h] > 0.f ? 1.f / psum[h] : 0.f;
      float4 o;
      o.x = acc[h][0] * inv; o.y = acc[h][1] * inv;
      o.z = acc[h][2] * inv; o.w = acc[h][3] * inv;
      *(float4*)&agg[(size_t)wid * DD + h * 64 + l * 4] = o;
    }
  }
}

// ---------------- generic GEMM (col-fastest grid, 128x128, BK=32, 2-phase LDS double-buffer) ----------------
// T3 minimum-2-phase: issue next tile's global_load_lds BEFORE computing current tile;
// one vmcnt(0)+barrier per K-step (explicit asm so the prefetch stays in flight across MFMAs).
#define BM 128
#define BN 128
#define BK 32

enum { M_QKVS = 0, M_BF16 = 1, M_GELU = 2, M_RES = 3 };

template <int MODE>
__global__ __launch_bounds__(256) void gemm_k(const __hip_bfloat16* __restrict__ A,
                                              const __hip_bfloat16* __restrict__ BT,
                                              const float* __restrict__ bias,
                                              const float* __restrict__ res,
                                              void* __restrict__ out0, void* __restrict__ out1,
                                              int M, int K, int Nn) {
  __shared__ short lA[2][BM * BK];   // 2 x 8 KB
  __shared__ short lB[2][BN * BK];   // 2 x 8 KB
  int t = threadIdx.x;
  int lane = t & 63, w = t >> 6;
  int wr = (w >> 1) * 64, wc = (w & 1) * 64;
  int row0 = blockIdx.y * BM, col0 = blockIdx.x * BN;   // col-fastest
  int lr = lane & 15, lk = lane >> 4;
  f32x4 acc[4][4] = {};

  auto stage = [&](int b, int kt) {
#pragma unroll
    for (int j = 0; j < 2; ++j) {
      int chunk = j * 256 + t;
      int r = chunk >> 2, kc = chunk & 3;
      int wavebase = (j * 256 + w * 64) * 8;   // wave-uniform LDS base (shorts)
      int gra = row0 + r; gra = gra < M ? gra : M - 1;
      gload_lds16(A + (size_t)gra * K + kt + kc * 8, &lA[b][wavebase]);
      gload_lds16(BT + (size_t)(col0 + r) * K + kt + kc * 8, &lB[b][wavebase]);
    }
  };

  stage(0, 0);
  asm volatile("s_waitcnt vmcnt(0)" ::: "memory");
  __builtin_amdgcn_s_barrier();
  int nt = K / BK, cur = 0;
  for (int ti = 0; ti < nt; ++ti) {
    if (ti + 1 < nt) stage(cur ^ 1, (ti + 1) * BK);
    bf16x8 af[4], bfr[4];
#pragma unroll
    for (int mi = 0; mi < 4; ++mi)
      af[mi] = *(const bf16x8*)&lA[cur][(wr + mi * 16 + lr) * BK + lk * 8];
#pragma unroll
    for (int ni = 0; ni < 4; ++ni)
      bfr[ni] = *(const bf16x8*)&lB[cur][(wc + ni * 16 + lr) * BK + lk * 8];
#pragma unroll
    for (int mi = 0; mi < 4; ++mi)
#pragma unroll
      for (int ni = 0; ni < 4; ++ni)
        acc[mi][ni] = __builtin_amdgcn_mfma_f32_16x16x32_bf16(af[mi], bfr[ni], acc[mi][ni], 0, 0, 0);
    asm volatile("s_waitcnt vmcnt(0)" ::: "memory");
    __builtin_amdgcn_s_barrier();
    cur ^= 1;
  }

#pragma unroll
  for (int mi = 0; mi < 4; ++mi) {
#pragma unroll
    for (int r = 0; r < 4; ++r) {
      int row = row0 + wr + mi * 16 + lk * 4 + r;
      if (row >= M) continue;
#pragma unroll
      for (int ni = 0; ni < 4; ++ni) {
        int col = col0 + wc + ni * 16 + lr;
        float v = acc[mi][ni][r];
        if constexpr (MODE == M_QKVS) {
          v += bias[col];
          if (col < 1152)
            ((__hip_bfloat16*)out0)[(size_t)row * 1152 + col] = __float2bfloat16(v);
          else
            ((float*)out1)[(size_t)row * DD + (col - 1152)] = v;
        } else if constexpr (MODE == M_BF16) {
          ((__hip_bfloat16*)out0)[(size_t)row * Nn + col] = __float2bfloat16(v);
        } else if constexpr (MODE == M_GELU) {
          v += bias[col];
          v = 0.5f * v * (1.f + erff(v * 0.70710678118f));
          ((__hip_bfloat16*)out0)[(size_t)row * Nn + col] = __float2bfloat16(v);
        } else {  // M_RES
          v += bias[col];
          ((float*)out0)[(size_t)row * Nn + col] = v + res[(size_t)row * Nn + col];
        }
      }
    }
  }
}

// ---------------- edge GEMM, full-width, 2-phase dbuf, A staged as raw f32 via global_load_lds ----------------
// A (f32) goes straight to LDS async (no VGPR round-trip); cvt to bf16 happens in-register at
// fragment read (VALU, overlaps MFMA pipe). A chunks XOR-swizzled by (row&7) — both-sides
// involution (rule #21): linear LDS dest + pre-swizzled SOURCE chunk + swizzled READ chunk.
// LDS = 2*(16KB A + 24KB B) = 80KB -> exactly 2 blocks/CU.
__global__ __launch_bounds__(256, 2) void gemm_edge_wide(const float* __restrict__ A,
                                                         const __hip_bfloat16* __restrict__ BT,
                                                         __hip_bfloat16* __restrict__ out, int M) {
  __shared__ float lAf[2][BM * BK];      // 2 x 128x32 f32 = 2 x 16 KB
  __shared__ short lB[2][DD * BK];       // 2 x 384x32 bf16 = 2 x 24 KB
  int t = threadIdx.x;
  int lane = t & 63, w = t >> 6;
  int wr = (w >> 1) * 64, wc = (w & 1) * 192;
  int row0 = blockIdx.x * BM;
  int lr = lane & 15, lk = lane >> 4;
  f32x4 acc[4][12] = {};

  auto stage = [&](int b, int kt) {
    // B: 384 rows x 4 chunks = 1536 chunks, 6 per thread, linear
#pragma unroll
    for (int pss = 0; pss < 6; ++pss) {
      int c = pss * 256 + t;
      int r = c >> 2, kc = c & 3;
      int wavebase = (pss * 256 + w * 64) * 8;
      gload_lds16(BT + (size_t)r * DD + kt + kc * 8, &lB[b][wavebase]);
    }
    // A: 128 rows x 8 chunks (16B = 4 f32) = 1024 chunks, 4 per thread;
    // linear LDS slot, source chunk = slot ^ (row&7)
#pragma unroll
    for (int pss = 0; pss < 4; ++pss) {
      int c = pss * 256 + t;
      int r = c >> 3, slot = c & 7;
      int kc = slot ^ (r & 7);
      int gra = row0 + r; gra = gra < M ? gra : M - 1;
      int wavebase = (pss * 256 + w * 64) * 4;   // floats
      gload_lds16(A + (size_t)gra * DD + kt + kc * 4, &lAf[b][wavebase]);
    }
  };

  stage(0, 0);
  asm volatile("s_waitcnt vmcnt(0)" ::: "memory");
  __builtin_amdgcn_s_barrier();
  int nt = DD / BK, cur = 0;
  for (int ti = 0; ti < nt; ++ti) {
    if (ti + 1 < nt) stage(cur ^ 1, (ti + 1) * BK);
    // A fragments: read swizzled f32 chunks, cvt to bf16 in-register
    bf16x8 af[4];
#pragma unroll
    for (int mi = 0; mi < 4; ++mi) {
      int r = wr + mi * 16 + lr;
      int base = r * BK;                              // 32 f32 per row
      float4 fa = *(const float4*)&lAf[cur][base + (((2 * lk)) ^ (lr & 7)) * 4];
      float4 fb = *(const float4*)&lAf[cur][base + (((2 * lk + 1)) ^ (lr & 7)) * 4];
      bf16x8 v;
      v[0] = f2bf(fa.x); v[1] = f2bf(fa.y); v[2] = f2bf(fa.z); v[3] = f2bf(fa.w);
      v[4] = f2bf(fb.x); v[5] = f2bf(fb.y); v[6] = f2bf(fb.z); v[7] = f2bf(fb.w);
      af[mi] = v;
    }
#pragma unroll
    for (int ni = 0; ni < 12; ++ni) {
      bf16x8 bfr = *(const bf16x8*)&lB[cur][(wc + ni * 16 + lr) * BK + lk * 8];
#pragma unroll
      for (int mi = 0; mi < 4; ++mi)
        acc[mi][ni] = __builtin_amdgcn_mfma_f32_16x16x32_bf16(af[mi], bfr, acc[mi][ni], 0, 0, 0);
    }
    asm volatile("s_waitcnt vmcnt(0)" ::: "memory");
    __builtin_amdgcn_s_barrier();
    cur ^= 1;
  }

#pragma unroll
  for (int mi = 0; mi < 4; ++mi) {
#pragma unroll
    for (int r = 0; r < 4; ++r) {
      int row = row0 + wr + mi * 16 + lk * 4 + r;
      if (row >= M) continue;
#pragma unroll
      for (int ni = 0; ni < 12; ++ni) {
        int col = wc + ni * 16 + lr;
        out[(size_t)row * DD + col] = __float2bfloat16(acc[mi][ni][r]);
      }
    }
  }
}

// ---------------- host ----------------
extern "C" void kernel_launch(void* const* d_in, const int* in_sizes, int n_in,
                              void* d_out, int out_size, void* d_ws, size_t ws_size,
                              hipStream_t stream) {
  const float* x   = (const float*)d_in[0];
  const int*   ei  = (const int*)d_in[1];
  const float* ea  = (const float*)d_in[2];
  const float* g1  = (const float*)d_in[3];
  const float* b1  = (const float*)d_in[4];
  const float* Wq  = (const float*)d_in[5];
  const float* bq  = (const float*)d_in[6];
  const float* Wk  = (const float*)d_in[7];
  const float* bk  = (const float*)d_in[8];
  const float* Wv  = (const float*)d_in[9];
  const float* bv  = (const float*)d_in[10];
  const float* We  = (const float*)d_in[11];
  const float* Wsk = (const float*)d_in[12];
  const float* bsk = (const float*)d_in[13];
  const float* g2  = (const float*)d_in[14];
  const float* b2  = (const float*)d_in[15];
  const float* W1  = (const float*)d_in[16];
  const float* bm1 = (const float*)d_in[17];
  const float* W2  = (const float*)d_in[18];
  const float* bm2 = (const float*)d_in[19];

  int N = in_sizes[0] / DD;
  int E = in_sizes[1] / 2;

  char* ws = (char*)d_ws;
  size_t off = 0;
  auto alloc = [&](size_t bytes) -> char* {
    char* p = ws + off;
    off = (off + bytes + 255) & ~(size_t)255;
    return p;
  };

  float* bnsum = (float*)alloc(4 * DD * sizeof(float));  // sums1, sq1, sums2, sq2
  float* a1 = (float*)alloc(DD * 4);
  float* c1 = (float*)alloc(DD * 4);
  float* a2 = (float*)alloc(DD * 4);
  float* c2 = (float*)alloc(DD * 4);
  float* bqkvs = (float*)alloc(1536 * 4);
  __hip_bfloat16* WqkvsT = (__hip_bfloat16*)alloc((size_t)1536 * DD * 2);
  __hip_bfloat16* WeT = (__hip_bfloat16*)alloc((size_t)DD * DD * 2);
  __hip_bfloat16* W1T = (__hip_bfloat16*)alloc((size_t)DHID * DD * 2);
  __hip_bfloat16* W2T = (__hip_bfloat16*)alloc((size_t)DD * DHID * 2);
  __hip_bfloat16* hbuf = (__hip_bfloat16*)alloc((size_t)N * DD * 2);   // h, later h2
  __hip_bfloat16* qkv = (__hip_bfloat16*)alloc((size_t)N * 1152 * 2);
  float* skip = (float*)alloc((size_t)N * DD * 4);
  __hip_bfloat16* ebuf = (__hip_bfloat16*)alloc((size_t)E * DD * 2);
  float* agg = (float*)alloc((size_t)N * DD * 4);
  float* x1 = (float*)alloc((size_t)N * DD * 4);
  __hip_bfloat16* hid = (__hip_bfloat16*)alloc((size_t)N * DHID * 2);
  int* deg = (int*)alloc((size_t)N * 4);
  int* cursor = (int*)alloc((size_t)N * 4);
  int* row_start = (int*)alloc((size_t)(N + 1) * 4);
  int* csr_src = (int*)alloc((size_t)E * 4);
  int* csr_eid = (int*)alloc((size_t)E * 4);
  (void)ws_size; (void)n_in; (void)out_size;

  hipMemsetAsync(bnsum, 0, 4 * DD * sizeof(float), stream);
  hipMemsetAsync(deg, 0, (size_t)N * 4, stream);

  int rpb = 128, sgrid = (N + rpb - 1) / rpb;
  bn_stats_k<<<sgrid, DD, 0, stream>>>(x, bnsum, bnsum + DD, N, rpb);
  bn_finalize_k<<<2, 256, 0, stream>>>(bnsum, bnsum + DD, g1, b1, a1, c1, N);

  int t4 = N * DD / 4;
  norm_to_bf16_k<<<(t4 + 255) / 256, 256, 0, stream>>>(x, a1, c1, hbuf, t4);

  int wgrid = (DD * DD + 255) / 256;
  transpose_bf16_k<<<wgrid, 256, 0, stream>>>(Wq, WqkvsT, DD, DD);
  transpose_bf16_k<<<wgrid, 256, 0, stream>>>(Wk, WqkvsT + (size_t)DD * DD, DD, DD);
  transpose_bf16_k<<<wgrid, 256, 0, stream>>>(Wv, WqkvsT + (size_t)2 * DD * DD, DD, DD);
  transpose_bf16_k<<<wgrid, 256, 0, stream>>>(Wsk, WqkvsT + (size_t)3 * DD * DD, DD, DD);
  transpose_bf16_k<<<wgrid, 256, 0, stream>>>(We, WeT, DD, DD);
  transpose_bf16_k<<<(DD * DHID + 255) / 256, 256, 0, stream>>>(W1, W1T, DD, DHID);
  transpose_bf16_k<<<(DHID * DD + 255) / 256, 256, 0, stream>>>(W2, W2T, DHID, DD);
  concat_bias_k<<<6, 256, 0, stream>>>(bq, bk, bv, bsk, bqkvs);

  // col-fastest grids: (ncols, nrows)
  dim3 gqkvs(1536 / BN, (N + BM - 1) / BM);
  gemm_k<M_QKVS><<<gqkvs, 256, 0, stream>>>(hbuf, WqkvsT, bqkvs, nullptr, qkv, skip, N, DD, 1536);

  // edge GEMM: full-width blocks, A read exactly once, async f32 staging
  gemm_edge_wide<<<(E + BM - 1) / BM, 256, 0, stream>>>(ea, WeT, ebuf, E);

  hist_k<<<(E + 255) / 256, 256, 0, stream>>>(ei, deg, E);
  scan_k<<<1, 1024, 0, stream>>>(deg, row_start, cursor, N);
  scatter_k<<<(E + 255) / 256, 256, 0, stream>>>(ei, cursor, csr_src, csr_eid, E);

  attn_k<<<(N * 64 + 255) / 256, 256, 0, stream>>>(qkv, ebuf, row_start, csr_src, csr_eid, agg, N);

  add3_k<<<(t4 + 255) / 256, 256, 0, stream>>>(x, agg, skip, x1, t4);

  bn_stats_k<<<sgrid, DD, 0, stream>>>(x1, bnsum + 2 * DD, bnsum + 3 * DD, N, rpb);
  bn_finalize_k<<<2, 256, 0, stream>>>(bnsum + 2 * DD, bnsum + 3 * DD, g2, b2, a2, c2, N);
  norm_to_bf16_k<<<(t4 + 255) / 256, 256, 0, stream>>>(x1, a2, c2, hbuf, t4);

  dim3 gm1(DHID / BN, (N + BM - 1) / BM);
  gemm_k<M_GELU><<<gm1, 256, 0, stream>>>(hbuf, W1T, bm1, nullptr, hid, nullptr, N, DD, DHID);

  dim3 gm2(DD / BN, (N + BM - 1) / BM);
  gemm_k<M_RES><<<gm2, 256, 0, stream>>>(hid, W2T, bm2, x1, (float*)d_out, nullptr, N, DHID, DD);
}

// Round 13
// 559.658 us; speedup vs baseline: 1.0819x; 1.0678x over previous
//

#include <hip/hip_runtime.h>
#include <hip/hip_bf16.h>

#define DD 384
#define NH 6
#define DHID 768

typedef __attribute__((ext_vector_type(8))) short bf16x8;
typedef __attribute__((ext_vector_type(4))) float f32x4;

__device__ __forceinline__ void gload_lds16(const void* gsrc, void* ldst) {
  __builtin_amdgcn_global_load_lds((const __attribute__((address_space(1))) void*)gsrc,
                                   (__attribute__((address_space(3))) void*)ldst,
                                   16, 0, 0);
}

__device__ __forceinline__ float b2f(unsigned short u) {
  union { unsigned int i; float f; } c;
  c.i = (unsigned int)u << 16;
  return c.f;
}

// ---------------- BatchNorm ----------------
__global__ __launch_bounds__(384) void bn_stats_k(const float* __restrict__ x, float* __restrict__ sums,
                                                  float* __restrict__ sq, int N, int rpb) {
  int d = threadIdx.x;
  int r0 = blockIdx.x * rpb;
  int r1 = min(r0 + rpb, N);
  float s = 0.f, ss = 0.f;
  for (int r = r0; r < r1; ++r) {
    float v = x[(size_t)r * DD + d];
    s += v; ss += v * v;
  }
  atomicAdd(&sums[d], s);
  atomicAdd(&sq[d], ss);
}

__global__ void bn_finalize_k(const float* sums, const float* sq, const float* g, const float* b,
                              float* a, float* c, int N) {
  int d = blockIdx.x * blockDim.x + threadIdx.x;
  if (d >= DD) return;
  float inv = 1.f / (float)N;
  float mu = sums[d] * inv;
  float var = sq[d] * inv - mu * mu;
  float rs = rsqrtf(var + 1e-5f);
  a[d] = rs * g[d];
  c[d] = b[d] - mu * rs * g[d];
}

union BPack { ushort4 u; __hip_bfloat16 b[4]; };

__global__ void norm_to_bf16_k(const float* __restrict__ x, const float* __restrict__ a,
                               const float* __restrict__ c, __hip_bfloat16* __restrict__ h, int total4) {
  int i = blockIdx.x * blockDim.x + threadIdx.x;
  if (i >= total4) return;
  float4 v = ((const float4*)x)[i];
  int d0 = (i * 4) % DD;
  float4 av = *(const float4*)(a + d0);
  float4 cv = *(const float4*)(c + d0);
  BPack p;
  p.b[0] = __float2bfloat16(v.x * av.x + cv.x);
  p.b[1] = __float2bfloat16(v.y * av.y + cv.y);
  p.b[2] = __float2bfloat16(v.z * av.z + cv.z);
  p.b[3] = __float2bfloat16(v.w * av.w + cv.w);
  ((ushort4*)h)[i] = p.u;
}

// ---------------- merged weight prep: 7 transposes + bias concat in one kernel ----------------
__global__ void prep_k(const float* __restrict__ Wq, const float* __restrict__ Wk,
                       const float* __restrict__ Wv, const float* __restrict__ Wsk,
                       const float* __restrict__ We, const float* __restrict__ W1,
                       const float* __restrict__ W2,
                       const float* __restrict__ bq, const float* __restrict__ bk,
                       const float* __restrict__ bv, const float* __restrict__ bsk,
                       __hip_bfloat16* __restrict__ WqkvsT, __hip_bfloat16* __restrict__ WeT,
                       __hip_bfloat16* __restrict__ W1T, __hip_bfloat16* __restrict__ W2T,
                       float* __restrict__ bqkvs) {
  const int S0 = 4 * 147456, S1 = S0 + 147456, S2 = S1 + 294912, S3 = S2 + 294912, S4 = S3 + 1536;
  int i = blockIdx.x * blockDim.x + threadIdx.x;
  if (i < S0) {
    int which = i / 147456, j = i % 147456;
    int k = j / 384, n = j % 384;
    const float* W = which == 0 ? Wq : which == 1 ? Wk : which == 2 ? Wv : Wsk;
    WqkvsT[(size_t)which * 147456 + n * 384 + k] = __float2bfloat16(W[j]);
  } else if (i < S1) {
    int j = i - S0, k = j / 384, n = j % 384;
    WeT[(size_t)n * 384 + k] = __float2bfloat16(We[j]);
  } else if (i < S2) {
    int j = i - S1, k = j / 768, n = j % 768;
    W1T[(size_t)n * 384 + k] = __float2bfloat16(W1[j]);
  } else if (i < S3) {
    int j = i - S2, k = j / 384, n = j % 384;
    W2T[(size_t)n * 768 + k] = __float2bfloat16(W2[j]);
  } else if (i < S4) {
    int j = i - S3;
    float v = (j < 384) ? bq[j] : (j < 768) ? bk[j - 384] : (j < 1152) ? bv[j - 768] : bsk[j - 1152];
    bqkvs[j] = v;
  }
}

__global__ void add3_k(const float* __restrict__ x, const float* __restrict__ agg,
                       const float* __restrict__ skip, float* __restrict__ x1, int total4) {
  int i = blockIdx.x * blockDim.x + threadIdx.x;
  if (i >= total4) return;
  float4 a = ((const float4*)x)[i];
  float4 b = ((const float4*)agg)[i];
  float4 c = ((const float4*)skip)[i];
  float4 o;
  o.x = a.x + b.x + c.x; o.y = a.y + b.y + c.y;
  o.z = a.z + b.z + c.z; o.w = a.w + b.w + c.w;
  ((float4*)x1)[i] = o;
}

// ---------------- CSR build (parallel two-level scan) ----------------
__global__ void hist_k(const int* __restrict__ ei, int* __restrict__ deg, int E) {
  int i = blockIdx.x * blockDim.x + threadIdx.x;
  if (i < E) atomicAdd(&deg[ei[E + i]], 1);
}

__global__ __launch_bounds__(1024) void scan1_k(const int* __restrict__ deg, int* __restrict__ incl,
                                                int* __restrict__ part, int N) {
  __shared__ int sh[1024];
  int t = threadIdx.x, i = blockIdx.x * 1024 + t;
  int v = (i < N) ? deg[i] : 0;
  sh[t] = v;
  __syncthreads();
  for (int off = 1; off < 1024; off <<= 1) {
    int u = (t >= off) ? sh[t - off] : 0;
    __syncthreads();
    sh[t] += u;
    __syncthreads();
  }
  if (i < N) incl[i] = sh[t];
  if (t == 1023) part[blockIdx.x] = sh[1023];
}

__global__ void scan2_k(const int* __restrict__ part, int* __restrict__ partx, int nblk) {
  if (threadIdx.x == 0 && blockIdx.x == 0) {
    int run = 0;
    for (int b = 0; b < nblk; ++b) { partx[b] = run; run += part[b]; }
    partx[nblk] = run;
  }
}

__global__ __launch_bounds__(1024) void scan3_k(const int* __restrict__ deg, const int* __restrict__ incl,
                                                const int* __restrict__ partx, int* __restrict__ row_start,
                                                int* __restrict__ cursor, int N, int nblk) {
  int i = blockIdx.x * 1024 + threadIdx.x;
  if (i >= N) return;
  int ex = partx[blockIdx.x] + incl[i] - deg[i];
  row_start[i] = ex;
  cursor[i] = ex;
  if (i == N - 1) row_start[N] = partx[nblk];
}

__global__ void scatter_k(const int* __restrict__ ei, int* __restrict__ cursor,
                          int* __restrict__ csr_src, int* __restrict__ pos_of_eid, int E) {
  int i = blockIdx.x * blockDim.x + threadIdx.x;
  if (i >= E) return;
  int s = ei[i], d = ei[E + i];
  int pos = atomicAdd(&cursor[d], 1);
  csr_src[pos] = s;
  pos_of_eid[i] = pos;
}

// ---------------- attention (ebuf already CSR-ordered: sequential reads, no eid gather) ----------------
__global__ __launch_bounds__(256) void attn_k(const __hip_bfloat16* __restrict__ qkv,
                                              const __hip_bfloat16* __restrict__ ebuf,
                                              const int* __restrict__ row_start,
                                              const int* __restrict__ csr_src,
                                              float* __restrict__ agg, int N) {
  int wid = (blockIdx.x * blockDim.x + threadIdx.x) >> 6;
  int lane = threadIdx.x & 63;
  if (wid >= N) return;
  int g = lane >> 4, l = lane & 15;
  const ushort* qk = (const ushort*)qkv;
  const ushort* eu = (const ushort*)ebuf;
  float q[NH][4], acc[NH][4], psum[NH];
#pragma unroll
  for (int h = 0; h < NH; ++h) {
    ushort4 u = *(const ushort4*)&qk[(size_t)wid * 1152 + h * 64 + l * 4];
    q[h][0] = b2f(u.x); q[h][1] = b2f(u.y); q[h][2] = b2f(u.z); q[h][3] = b2f(u.w);
#pragma unroll
    for (int j = 0; j < 4; ++j) acc[h][j] = 0.f;
    psum[h] = 0.f;
  }
  int i0 = row_start[wid], i1 = row_start[wid + 1];
  for (int i = i0; i < i1; i += 4) {
    int e = i + g;
    bool valid = e < i1;
    int ec = valid ? e : i1 - 1;
    size_t sb = (size_t)csr_src[ec] * 1152;
    size_t eb = (size_t)ec * 384;     // sequential: 4 consecutive rows per wave-iteration
    float ev[NH][4], p[NH];
#pragma unroll
    for (int h = 0; h < NH; ++h) {
      ushort4 ue = *(const ushort4*)&eu[eb + h * 64 + l * 4];
      ev[h][0] = b2f(ue.x); ev[h][1] = b2f(ue.y); ev[h][2] = b2f(ue.z); ev[h][3] = b2f(ue.w);
      ushort4 uk = *(const ushort4*)&qk[sb + 384 + h * 64 + l * 4];
      float t = q[h][0] * (b2f(uk.x) + ev[h][0]);
      t += q[h][1] * (b2f(uk.y) + ev[h][1]);
      t += q[h][2] * (b2f(uk.z) + ev[h][2]);
      t += q[h][3] * (b2f(uk.w) + ev[h][3]);
      t += __shfl_xor(t, 1);
      t += __shfl_xor(t, 2);
      t += __shfl_xor(t, 4);
      t += __shfl_xor(t, 8);
      p[h] = valid ? __expf(t * 0.125f) : 0.f;
    }
#pragma unroll
    for (int h = 0; h < NH; ++h) {
      ushort4 uv = *(const ushort4*)&qk[sb + 768 + h * 64 + l * 4];
      acc[h][0] += p[h] * (b2f(uv.x) + ev[h][0]);
      acc[h][1] += p[h] * (b2f(uv.y) + ev[h][1]);
      acc[h][2] += p[h] * (b2f(uv.z) + ev[h][2]);
      acc[h][3] += p[h] * (b2f(uv.w) + ev[h][3]);
      psum[h] += p[h];
    }
  }
#pragma unroll
  for (int h = 0; h < NH; ++h) {
#pragma unroll
    for (int j = 0; j < 4; ++j) {
      acc[h][j] += __shfl_xor(acc[h][j], 16);
      acc[h][j] += __shfl_xor(acc[h][j], 32);
    }
    psum[h] += __shfl_xor(psum[h], 16);
    psum[h] += __shfl_xor(psum[h], 32);
  }
  if (lane < 16) {
#pragma unroll
    for (int h = 0; h < NH; ++h) {
      float inv = psum[h] > 0.f ? 1.f / psum[h] : 0.f;
      float4 o;
      o.x = acc[h][0] * inv; o.y = acc[h][1] * inv;
      o.z = acc[h][2] * inv; o.w = acc[h][3] * inv;
      *(float4*)&agg[(size_t)wid * DD + h * 64 + l * 4] = o;
    }
  }
}

// ---------------- generic GEMM (col-fastest grid, 128x128, BK=32, 2-phase LDS double-buffer) ----------------
#define BM 128
#define BN 128
#define BK 32

enum { M_QKVS = 0, M_BF16 = 1, M_GELU = 2, M_RES = 3 };

template <int MODE>
__global__ __launch_bounds__(256) void gemm_k(const __hip_bfloat16* __restrict__ A,
                                              const __hip_bfloat16* __restrict__ BT,
                                              const float* __restrict__ bias,
                                              const float* __restrict__ res,
                                              void* __restrict__ out0, void* __restrict__ out1,
                                              int M, int K, int Nn) {
  __shared__ short lA[2][BM * BK];
  __shared__ short lB[2][BN * BK];
  int t = threadIdx.x;
  int lane = t & 63, w = t >> 6;
  int wr = (w >> 1) * 64, wc = (w & 1) * 64;
  int row0 = blockIdx.y * BM, col0 = blockIdx.x * BN;   // col-fastest
  int lr = lane & 15, lk = lane >> 4;
  f32x4 acc[4][4] = {};

  auto stage = [&](int b, int kt) {
#pragma unroll
    for (int j = 0; j < 2; ++j) {
      int chunk = j * 256 + t;
      int r = chunk >> 2, kc = chunk & 3;
      int wavebase = (j * 256 + w * 64) * 8;
      int gra = row0 + r; gra = gra < M ? gra : M - 1;
      gload_lds16(A + (size_t)gra * K + kt + kc * 8, &lA[b][wavebase]);
      gload_lds16(BT + (size_t)(col0 + r) * K + kt + kc * 8, &lB[b][wavebase]);
    }
  };

  stage(0, 0);
  asm volatile("s_waitcnt vmcnt(0)" ::: "memory");
  __builtin_amdgcn_s_barrier();
  int nt = K / BK, cur = 0;
  for (int ti = 0; ti < nt; ++ti) {
    if (ti + 1 < nt) stage(cur ^ 1, (ti + 1) * BK);
    bf16x8 af[4], bfr[4];
#pragma unroll
    for (int mi = 0; mi < 4; ++mi)
      af[mi] = *(const bf16x8*)&lA[cur][(wr + mi * 16 + lr) * BK + lk * 8];
#pragma unroll
    for (int ni = 0; ni < 4; ++ni)
      bfr[ni] = *(const bf16x8*)&lB[cur][(wc + ni * 16 + lr) * BK + lk * 8];
#pragma unroll
    for (int mi = 0; mi < 4; ++mi)
#pragma unroll
      for (int ni = 0; ni < 4; ++ni)
        acc[mi][ni] = __builtin_amdgcn_mfma_f32_16x16x32_bf16(af[mi], bfr[ni], acc[mi][ni], 0, 0, 0);
    asm volatile("s_waitcnt vmcnt(0)" ::: "memory");
    __builtin_amdgcn_s_barrier();
    cur ^= 1;
  }

#pragma unroll
  for (int mi = 0; mi < 4; ++mi) {
#pragma unroll
    for (int r = 0; r < 4; ++r) {
      int row = row0 + wr + mi * 16 + lk * 4 + r;
      if (row >= M) continue;
#pragma unroll
      for (int ni = 0; ni < 4; ++ni) {
        int col = col0 + wc + ni * 16 + lr;
        float v = acc[mi][ni][r];
        if constexpr (MODE == M_QKVS) {
          v += bias[col];
          if (col < 1152)
            ((__hip_bfloat16*)out0)[(size_t)row * 1152 + col] = __float2bfloat16(v);
          else
            ((float*)out1)[(size_t)row * DD + (col - 1152)] = v;
        } else if constexpr (MODE == M_BF16) {
          ((__hip_bfloat16*)out0)[(size_t)row * Nn + col] = __float2bfloat16(v);
        } else if constexpr (MODE == M_GELU) {
          v += bias[col];
          v = 0.5f * v * (1.f + erff(v * 0.70710678118f));
          ((__hip_bfloat16*)out0)[(size_t)row * Nn + col] = __float2bfloat16(v);
        } else {  // M_RES
          v += bias[col];
          ((float*)out0)[(size_t)row * Nn + col] = v + res[(size_t)row * Nn + col];
        }
      }
    }
  }
}

// ---------------- edge GEMM, full-width, 2-phase dbuf, f32 A via global_load_lds, CSR-perm output ----------------
__global__ __launch_bounds__(256, 2) void gemm_edge_wide(const float* __restrict__ A,
                                                         const __hip_bfloat16* __restrict__ BT,
                                                         const int* __restrict__ perm,
                                                         __hip_bfloat16* __restrict__ out, int M) {
  __shared__ float lAf[2][BM * BK];      // 2 x 16 KB
  __shared__ short lB[2][DD * BK];       // 2 x 24 KB
  int t = threadIdx.x;
  int lane = t & 63, w = t >> 6;
  int wr = (w >> 1) * 64, wc = (w & 1) * 192;
  int row0 = blockIdx.x * BM;
  int lr = lane & 15, lk = lane >> 4;
  f32x4 acc[4][12] = {};

  auto stage = [&](int b, int kt) {
#pragma unroll
    for (int pss = 0; pss < 6; ++pss) {
      int c = pss * 256 + t;
      int r = c >> 2, kc = c & 3;
      int wavebase = (pss * 256 + w * 64) * 8;
      gload_lds16(BT + (size_t)r * DD + kt + kc * 8, &lB[b][wavebase]);
    }
#pragma unroll
    for (int pss = 0; pss < 4; ++pss) {
      int c = pss * 256 + t;
      int r = c >> 3, slot = c & 7;
      int kc = slot ^ (r & 7);
      int gra = row0 + r; gra = gra < M ? gra : M - 1;
      int wavebase = (pss * 256 + w * 64) * 4;
      gload_lds16(A + (size_t)gra * DD + kt + kc * 4, &lAf[b][wavebase]);
    }
  };

  stage(0, 0);
  asm volatile("s_waitcnt vmcnt(0)" ::: "memory");
  __builtin_amdgcn_s_barrier();
  int nt = DD / BK, cur = 0;
  for (int ti = 0; ti < nt; ++ti) {
    if (ti + 1 < nt) stage(cur ^ 1, (ti + 1) * BK);
    bf16x8 af[4];
#pragma unroll
    for (int mi = 0; mi < 4; ++mi) {
      int r = wr + mi * 16 + lr;
      int base = r * BK;
      float4 fa = *(const float4*)&lAf[cur][base + (((2 * lk)) ^ (lr & 7)) * 4];
      float4 fb = *(const float4*)&lAf[cur][base + (((2 * lk + 1)) ^ (lr & 7)) * 4];
      bf16x8 v;
      union { __hip_bfloat16 h; short s; } u;
      u.h = __float2bfloat16(fa.x); v[0] = u.s;
      u.h = __float2bfloat16(fa.y); v[1] = u.s;
      u.h = __float2bfloat16(fa.z); v[2] = u.s;
      u.h = __float2bfloat16(fa.w); v[3] = u.s;
      u.h = __float2bfloat16(fb.x); v[4] = u.s;
      u.h = __float2bfloat16(fb.y); v[5] = u.s;
      u.h = __float2bfloat16(fb.z); v[6] = u.s;
      u.h = __float2bfloat16(fb.w); v[7] = u.s;
      af[mi] = v;
    }
#pragma unroll
    for (int ni = 0; ni < 12; ++ni) {
      bf16x8 bfr = *(const bf16x8*)&lB[cur][(wc + ni * 16 + lr) * BK + lk * 8];
#pragma unroll
      for (int mi = 0; mi < 4; ++mi)
        acc[mi][ni] = __builtin_amdgcn_mfma_f32_16x16x32_bf16(af[mi], bfr, acc[mi][ni], 0, 0, 0);
    }
    asm volatile("s_waitcnt vmcnt(0)" ::: "memory");
    __builtin_amdgcn_s_barrier();
    cur ^= 1;
  }

#pragma unroll
  for (int mi = 0; mi < 4; ++mi) {
#pragma unroll
    for (int r = 0; r < 4; ++r) {
      int row = row0 + wr + mi * 16 + lk * 4 + r;
      if (row >= M) continue;
      size_t orow = (size_t)perm[row];
#pragma unroll
      for (int ni = 0; ni < 12; ++ni) {
        int col = wc + ni * 16 + lr;
        out[orow * DD + col] = __float2bfloat16(acc[mi][ni][r]);
      }
    }
  }
}

// ---------------- host ----------------
extern "C" void kernel_launch(void* const* d_in, const int* in_sizes, int n_in,
                              void* d_out, int out_size, void* d_ws, size_t ws_size,
                              hipStream_t stream) {
  const float* x   = (const float*)d_in[0];
  const int*   ei  = (const int*)d_in[1];
  const float* ea  = (const float*)d_in[2];
  const float* g1  = (const float*)d_in[3];
  const float* b1  = (const float*)d_in[4];
  const float* Wq  = (const float*)d_in[5];
  const float* bq  = (const float*)d_in[6];
  const float* Wk  = (const float*)d_in[7];
  const float* bk  = (const float*)d_in[8];
  const float* Wv  = (const float*)d_in[9];
  const float* bv  = (const float*)d_in[10];
  const float* We  = (const float*)d_in[11];
  const float* Wsk = (const float*)d_in[12];
  const float* bsk = (const float*)d_in[13];
  const float* g2  = (const float*)d_in[14];
  const float* b2  = (const float*)d_in[15];
  const float* W1  = (const float*)d_in[16];
  const float* bm1 = (const float*)d_in[17];
  const float* W2  = (const float*)d_in[18];
  const float* bm2 = (const float*)d_in[19];

  int N = in_sizes[0] / DD;
  int E = in_sizes[1] / 2;

  char* ws = (char*)d_ws;
  size_t off = 0;
  auto alloc = [&](size_t bytes) -> char* {
    char* p = ws + off;
    off = (off + bytes + 255) & ~(size_t)255;
    return p;
  };

  float* bnsum = (float*)alloc(4 * DD * sizeof(float));
  float* a1 = (float*)alloc(DD * 4);
  float* c1 = (float*)alloc(DD * 4);
  float* a2 = (float*)alloc(DD * 4);
  float* c2 = (float*)alloc(DD * 4);
  float* bqkvs = (float*)alloc(1536 * 4);
  __hip_bfloat16* WqkvsT = (__hip_bfloat16*)alloc((size_t)1536 * DD * 2);
  __hip_bfloat16* WeT = (__hip_bfloat16*)alloc((size_t)DD * DD * 2);
  __hip_bfloat16* W1T = (__hip_bfloat16*)alloc((size_t)DHID * DD * 2);
  __hip_bfloat16* W2T = (__hip_bfloat16*)alloc((size_t)DD * DHID * 2);
  __hip_bfloat16* hbuf = (__hip_bfloat16*)alloc((size_t)N * DD * 2);
  __hip_bfloat16* qkv = (__hip_bfloat16*)alloc((size_t)N * 1152 * 2);
  float* skip = (float*)alloc((size_t)N * DD * 4);
  __hip_bfloat16* ebuf = (__hip_bfloat16*)alloc((size_t)E * DD * 2);
  float* agg = (float*)alloc((size_t)N * DD * 4);
  float* x1 = (float*)alloc((size_t)N * DD * 4);
  __hip_bfloat16* hid = (__hip_bfloat16*)alloc((size_t)N * DHID * 2);
  int* deg = (int*)alloc((size_t)N * 4);
  int* cursor = (int*)alloc((size_t)N * 4);
  int* row_start = (int*)alloc((size_t)(N + 1) * 4);
  int* csr_src = (int*)alloc((size_t)E * 4);
  int* pos_of_eid = (int*)alloc((size_t)E * 4);
  int* incl = (int*)alloc((size_t)N * 4);
  int* part = (int*)alloc(64 * 4);
  int* partx = (int*)alloc(64 * 4);
  (void)ws_size; (void)n_in; (void)out_size;

  hipMemsetAsync(bnsum, 0, 4 * DD * sizeof(float), stream);
  hipMemsetAsync(deg, 0, (size_t)N * 4, stream);

  // CSR build (parallel scan); must precede edge GEMM (perm) and attn
  int nblk = (N + 1023) / 1024;
  hist_k<<<(E + 255) / 256, 256, 0, stream>>>(ei, deg, E);
  scan1_k<<<nblk, 1024, 0, stream>>>(deg, incl, part, N);
  scan2_k<<<1, 64, 0, stream>>>(part, partx, nblk);
  scan3_k<<<nblk, 1024, 0, stream>>>(deg, incl, partx, row_start, cursor, N, nblk);
  scatter_k<<<(E + 255) / 256, 256, 0, stream>>>(ei, cursor, csr_src, pos_of_eid, E);

  int rpb = 128, sgrid = (N + rpb - 1) / rpb;
  bn_stats_k<<<sgrid, DD, 0, stream>>>(x, bnsum, bnsum + DD, N, rpb);
  bn_finalize_k<<<2, 256, 0, stream>>>(bnsum, bnsum + DD, g1, b1, a1, c1, N);

  int t4 = N * DD / 4;
  norm_to_bf16_k<<<(t4 + 255) / 256, 256, 0, stream>>>(x, a1, c1, hbuf, t4);

  // merged weight prep (7 transposes + bias concat)
  const int PREP_TOT = 4 * 147456 + 147456 + 294912 + 294912 + 1536;
  prep_k<<<(PREP_TOT + 255) / 256, 256, 0, stream>>>(Wq, Wk, Wv, Wsk, We, W1, W2,
                                                     bq, bk, bv, bsk,
                                                     WqkvsT, WeT, W1T, W2T, bqkvs);

  // col-fastest grids: (ncols, nrows)
  dim3 gqkvs(1536 / BN, (N + BM - 1) / BM);
  gemm_k<M_QKVS><<<gqkvs, 256, 0, stream>>>(hbuf, WqkvsT, bqkvs, nullptr, qkv, skip, N, DD, 1536);

  // edge GEMM: full-width, CSR-ordered output (perm)
  gemm_edge_wide<<<(E + BM - 1) / BM, 256, 0, stream>>>(ea, WeT, pos_of_eid, ebuf, E);

  attn_k<<<(N * 64 + 255) / 256, 256, 0, stream>>>(qkv, ebuf, row_start, csr_src, agg, N);

  add3_k<<<(t4 + 255) / 256, 256, 0, stream>>>(x, agg, skip, x1, t4);

  bn_stats_k<<<sgrid, DD, 0, stream>>>(x1, bnsum + 2 * DD, bnsum + 3 * DD, N, rpb);
  bn_finalize_k<<<2, 256, 0, stream>>>(bnsum + 2 * DD, bnsum + 3 * DD, g2, b2, a2, c2, N);
  norm_to_bf16_k<<<(t4 + 255) / 256, 256, 0, stream>>>(x1, a2, c2, hbuf, t4);

  dim3 gm1(DHID / BN, (N + BM - 1) / BM);
  gemm_k<M_GELU><<<gm1, 256, 0, stream>>>(hbuf, W1T, bm1, nullptr, hid, nullptr, N, DD, DHID);

  dim3 gm2(DD / BN, (N + BM - 1) / BM);
  gemm_k<M_RES><<<gm2, 256, 0, stream>>>(hid, W2T, bm2, x1, (float*)d_out, nullptr, N, DHID, DD);
}